// Round 12
// baseline (108.015 us; speedup 1.0000x reference)
//
#include <hip/hip_runtime.h>
#include <hip/hip_bf16.h>
#include <math.h>

#define DIM   768
#define BATCH 32
#define SEQ   2048
#define SCALE 0.036084391824351615f  // 1/sqrt(768)

__device__ __forceinline__ float wave_sum(float v) {
#pragma unroll
    for (int o = 32; o > 0; o >>= 1) v += __shfl_xor(v, o, 64);
    return v;
}

__device__ __forceinline__ void fma4(float4& a, float s, const float4& c) {
    a.x += s * c.x; a.y += s * c.y; a.z += s * c.z; a.w += s * c.w;
}

// ---------------------------------------------------------------------------
// Device GEMM over K range [kbeg,kend): part[kcidx][Mtot][768] tile (r0, jt).
// Single A source. LDS passed in so branched callers share one allocation.
// ---------------------------------------------------------------------------
__device__ __forceinline__ void gemm_range(
        float (*As)[33], float (*Ws)[64],
        const float* __restrict__ A, int lda,
        const float* __restrict__ W,
        float* __restrict__ part, int Mtot, int r0, int jt,
        int kbeg, int kend, int kcidx) {
    const int t = threadIdx.x;
    const int j = t & 63;
    const int bg = t >> 6;
    float acc[8];
#pragma unroll
    for (int i = 0; i < 8; i++) acc[i] = 0.f;

    for (int k0 = kbeg; k0 < kend; k0 += 32) {
        {   // A tile 32x32
            int r  = t >> 3;
            int kk = (t & 7) * 4;
            float4 av = *(const float4*)(A + (long)(r0 + r) * lda + k0 + kk);
            As[r][kk] = av.x; As[r][kk + 1] = av.y; As[r][kk + 2] = av.z; As[r][kk + 3] = av.w;
        }
#pragma unroll
        for (int i = 0; i < 2; i++) {  // W tile 32x64, float4 loads
            int idx = t + i * 256;
            int row = idx >> 4, col4 = idx & 15;
            float4 wv = *(const float4*)(W + (long)(k0 + row) * DIM + jt + col4 * 4);
            *(float4*)&Ws[row][col4 * 4] = wv;
        }
        __syncthreads();
#pragma unroll 8
        for (int kk = 0; kk < 32; kk++) {
            float wv = Ws[kk][j];
#pragma unroll
            for (int i = 0; i < 8; i++) acc[i] += As[bg * 8 + i][kk] * wv;
        }
        __syncthreads();
    }
#pragma unroll
    for (int i = 0; i < 8; i++)
        part[((long)(kcidx * Mtot + r0 + bg * 8 + i)) * DIM + jt + j] = acc[i];
}

// ---------------------------------------------------------------------------
// K1: gemm1 (blocks 0-47: question @ W_pos[st], 4 K-chunks of 192) in
// parallel with gemm2-control (blocks 48-335: control @ W_cq rows 0-1535,
// 24 K-chunks of 64). Independent — no sync. grid = 336 x 256.
// ---------------------------------------------------------------------------
__global__ __launch_bounds__(256) void k1_kernel(
        const float* __restrict__ question, const float* __restrict__ W_pos,
        const int* __restrict__ step_ptr,
        const float* __restrict__ control, const float* __restrict__ W_cq,
        float* __restrict__ part1, float* __restrict__ part2) {
    __shared__ float As[32][33];
    __shared__ float Ws[32][64];
    const int i = blockIdx.x;
    if (i < 48) {
        const int jt = (i % 12) * 64;
        const int kc = i / 12;        // 0..3, K range [kc*192, +192)
        const float* Wp = W_pos + (long)step_ptr[0] * DIM * DIM;
        gemm_range(As, Ws, question, DIM, Wp, part1, 32, 0, jt,
                   kc * 192, kc * 192 + 192, kc);
    } else {
        const int m = i - 48;
        const int jt = (m % 12) * 64;
        const int kc = m / 12;        // 0..23, K range [kc*64, +64) < 1536
        gemm_range(As, Ws, control, 2 * DIM, W_cq, part2, 32, 0, jt,
                   kc * 64, kc * 64 + 64, kc);
    }
}

// ---------------------------------------------------------------------------
// K2: LN1 folded + gemm2-pa. grid = 144 x 256.
// Preamble: per-block LN1 stats from part1 (4 chunks, full rows), then the
// block's own pa slice [32 x 64] in LDS; GEMM consumes A straight from LDS.
// Writes part2[24+kcp].
// ---------------------------------------------------------------------------
__global__ __launch_bounds__(256) void gemm2pa_kernel(
        const float* __restrict__ part1, const float* __restrict__ b_pos,
        const int* __restrict__ step_ptr,
        const float* __restrict__ ln1_g, const float* __restrict__ ln1_b,
        const float* __restrict__ W_cq, float* __restrict__ part2) {
    const int i = blockIdx.x;          // 0..143
    const int jt = (i % 12) * 64;
    const int kcp = i / 12;            // 0..11: pa col chunk
    const int t = threadIdx.x;
    const int lane = t & 63, wave = t >> 6;
    const float* bp = b_pos + (long)step_ptr[0] * DIM;

    __shared__ float pa_sh[32][64];
    __shared__ float Ws[32][64];
    __shared__ float musha[32], rssha[32];

    // ---- LN1 stats: each wave handles 8 rows, full 768 cols, 4 chunks ----
    for (int r = wave * 8; r < wave * 8 + 8; ++r) {
        float s = 0.f, ss = 0.f;
        for (int cb = 0; cb < 12; ++cb) {
            int col = lane + cb * 64;
            float v = bp[col];
#pragma unroll
            for (int kc = 0; kc < 4; kc++)
                v += part1[((long)(kc * 32 + r)) * DIM + col];
            s += v; ss += v * v;
        }
        s = wave_sum(s); ss = wave_sum(ss);
        if (lane == 0) {
            float mu = s * (1.f / DIM);
            musha[r] = mu;
            rssha[r] = rsqrtf(ss * (1.f / DIM) - mu * mu + 1e-5f);
        }
    }
    __syncthreads();
    // ---- pa slice: cols [kcp*64, +64), LN+ReLU into LDS ----
    {
        int r  = t >> 3;
        int c0 = (t & 7) * 8;
#pragma unroll
        for (int cc = 0; cc < 8; ++cc) {
            int col = kcp * 64 + c0 + cc;
            float v = bp[col];
#pragma unroll
            for (int kc = 0; kc < 4; kc++)
                v += part1[((long)(kc * 32 + r)) * DIM + col];
            float y = (v - musha[r]) * rssha[r] * ln1_g[col] + ln1_b[col];
            pa_sh[r][c0 + cc] = y > 0.f ? y : 0.f;
        }
    }
    __syncthreads();
    // ---- GEMM: part2[24+kcp] = pa_sh @ W_cq[1536+kcp*64 ..][jt..] ----
    const int j = t & 63, bg = t >> 6;
    float acc[8];
#pragma unroll
    for (int q = 0; q < 8; q++) acc[q] = 0.f;
    const long krow0 = 1536 + (long)kcp * 64;
    for (int k0 = 0; k0 < 64; k0 += 32) {
#pragma unroll
        for (int q = 0; q < 2; q++) {
            int idx = t + q * 256;
            int row = idx >> 4, col4 = idx & 15;
            float4 wv = *(const float4*)(W_cq + (krow0 + k0 + row) * DIM + jt + col4 * 4);
            *(float4*)&Ws[row][col4 * 4] = wv;
        }
        __syncthreads();
#pragma unroll 8
        for (int kk = 0; kk < 32; kk++) {
            float wv = Ws[kk][j];
#pragma unroll
            for (int q = 0; q < 8; q++) acc[q] += pa_sh[bg * 8 + q][k0 + kk] * wv;
        }
        __syncthreads();
    }
#pragma unroll
    for (int q = 0; q < 8; q++)
        part2[((long)((24 + kcp) * 32 + bg * 8 + q)) * DIM + jt + j] = acc[q];
}

// ---------------------------------------------------------------------------
// gemm_partial (R3-proven): used for gemm3. Dual-source unused (A0==A1).
// ---------------------------------------------------------------------------
__global__ __launch_bounds__(256) void gemm_partial(
        const float* __restrict__ A0, int lda0,
        const float* __restrict__ W,
        float* __restrict__ part, int Mtot) {
    const int jt = blockIdx.x * 64;
    const int r0 = blockIdx.y * 32;
    const int kc = blockIdx.z;
    __shared__ float As[32][33];
    __shared__ float Ws[32][64];
    gemm_range(As, Ws, A0, 2 * DIM, W, part, Mtot, r0, jt,
               kc * 64, kc * 64 + 64, kc);
}

// Final: reduce + bias, dual LN, ReLU -> next_control. grid = 64, block 256.
__global__ __launch_bounds__(256) void reduce_ln_final(
        const float* __restrict__ part, int KC,
        const float* __restrict__ bias,
        const float* __restrict__ g3, const float* __restrict__ b3,
        const float* __restrict__ g4, const float* __restrict__ b4,
        float* __restrict__ nc) {
    const int row = blockIdx.x;  // 0..63
    const int t = threadIdx.x;
    __shared__ float r1[4], r2[4];
    float x[3];
    float s = 0.f, ss = 0.f;
#pragma unroll
    for (int i = 0; i < 3; i++) {
        int jj = t + i * 256;
        float v = bias[jj];
#pragma unroll 4
        for (int kc = 0; kc < KC; kc++)
            v += part[((long)(kc * 64 + row)) * DIM + jj];
        x[i] = v; s += v; ss += v * v;
    }
    float wsv = wave_sum(s), wss = wave_sum(ss);
    int lane = t & 63, wid = t >> 6;
    if (lane == 0) { r1[wid] = wsv; r2[wid] = wss; }
    __syncthreads();
    s  = r1[0] + r1[1] + r1[2] + r1[3];
    ss = r2[0] + r2[1] + r2[2] + r2[3];
    float mu = s * (1.f / DIM);
    float var = ss * (1.f / DIM) - mu * mu;
    float rs = rsqrtf(var + 1e-5f);
    const float* g  = (row < 32) ? g3 : g4;
    const float* bb = (row < 32) ? b3 : b4;
    int bidx = row & 31;
    int off  = (row < 32) ? 0 : DIM;
#pragma unroll
    for (int i = 0; i < 3; i++) {
        int jj = t + i * 256;
        float y = (x[i] - mu) * rs * g[jj] + bb[jj];
        nc[(long)bidx * (2 * DIM) + off + jj] = y > 0.f ? y : 0.f;
    }
}

// ---------------------------------------------------------------------------
// Fused attention with LN2 folded in (R11-proven).
// grid = (SEQ/128, BATCH), 512 threads (8 waves), CHUNK=128.
// ---------------------------------------------------------------------------
__global__ __launch_bounds__(512, 4) void attn_main(
        const float* __restrict__ ctx, const float* __restrict__ part2,
        const float* __restrict__ b_cq,
        const float* __restrict__ ln2_g, const float* __restrict__ ln2_b,
        const float* __restrict__ W_attn, const float* __restrict__ b_attn,
        const float* __restrict__ qm1, const float* __restrict__ qm2,
        float* __restrict__ w, float* __restrict__ zpart,
        float* __restrict__ pvec) {
    const int c = blockIdx.x;   // 0..15
    const int b = blockIdx.y;
    const int t = threadIdx.x;
    const int wave = t >> 6, lane = t & 63;
    __shared__ float4 red[3][192];   // 9216 B
    __shared__ float ush[DIM];       // 3072 B
    __shared__ float sc1[8], sc2[8];

    // ---- LN2 preamble: u[b] from part2 ----
    {
        float ua = b_cq[t];
        float ub = (t < 256) ? b_cq[t + 512] : 0.f;
#pragma unroll 4
        for (int kc = 0; kc < 36; kc++) {
            const float* p2 = part2 + ((long)(kc * 32 + b)) * DIM;
            ua += p2[t];
            if (t < 256) ub += p2[t + 512];
        }
        float v1 = wave_sum(ua + ub);
        float v2 = wave_sum(ua * ua + ub * ub);
        if (lane == 0) { sc1[wave] = v1; sc2[wave] = v2; }
        __syncthreads();
        float s = 0.f, ss = 0.f;
#pragma unroll
        for (int i = 0; i < 8; i++) { s += sc1[i]; ss += sc2[i]; }
        float mu = s * (1.f / DIM);
        float var = ss * (1.f / DIM) - mu * mu;
        float rs = rsqrtf(var + 1e-5f);
        float y = (ua - mu) * rs * ln2_g[t] + ln2_b[t];
        ush[t] = (y > 0.f ? y : 0.f) * W_attn[t];
        if (t < 256) {
            float y2 = (ub - mu) * rs * ln2_g[t + 512] + ln2_b[t + 512];
            ush[t + 512] = (y2 > 0.f ? y2 : 0.f) * W_attn[t + 512];
        }
        __syncthreads();
    }

    const float batt = b_attn[0];
    const long row0 = (long)b * SEQ + c * 128;

    float4 uu[3];
#pragma unroll
    for (int i = 0; i < 3; i++)
        uu[i] = ((const float4*)ush)[lane + i * 64];

    float4 acc[3][3];
#pragma unroll
    for (int k = 0; k < 3; k++)
#pragma unroll
        for (int i = 0; i < 3; i++) acc[k][i] = make_float4(0.f, 0.f, 0.f, 0.f);
    float zacc[3] = {0.f, 0.f, 0.f};

#pragma unroll 1
    for (int g = 0; g < 4; g++) {
        const int rw = g * 32 + wave * 4;
        float4 cr[4][3];
        float d[4];
#pragma unroll
        for (int rr = 0; rr < 4; rr++) {
            const float4* crow = (const float4*)(ctx + (row0 + rw + rr) * DIM);
            float dd = 0.f;
#pragma unroll
            for (int i = 0; i < 3; i++) {
                float4 cv = crow[lane + i * 64];
                cr[rr][i] = cv;
                dd += cv.x * uu[i].x + cv.y * uu[i].y + cv.z * uu[i].z + cv.w * uu[i].w;
            }
            d[rr] = wave_sum(dd);
        }
        float lw0 = (d[0] + batt) * SCALE;
        float lw1 = (d[1] + batt) * SCALE;
        float lw2 = (d[2] + batt) * SCALE;
        float lw3 = (d[3] + batt) * SCALE;
        if (lane < 4) {
            float v = lane == 0 ? lw0 : lane == 1 ? lw1 : lane == 2 ? lw2 : lw3;
            w[row0 + rw + lane] = v;
        }
        float mv = 0.f;
        if (lane < 4) mv = qm1[row0 + rw + lane];
        else if (lane < 8) mv = qm2[row0 + rw + lane - 4];
#pragma unroll
        for (int rr = 0; rr < 4; rr++) {
            float a1 = __shfl(mv, rr, 64);
            float a2 = __shfl(mv, rr + 4, 64);
            float lwr = rr == 0 ? lw0 : rr == 1 ? lw1 : rr == 2 ? lw2 : lw3;
            float ev = __expf(lwr);
            float e0 = (a1 != 0.f || a2 != 0.f) ? ev : 0.f;
            float e1 = (a1 != 0.f) ? ev : 0.f;
            float e2 = (a2 != 0.f) ? ev : 0.f;
            zacc[0] += e0; zacc[1] += e1; zacc[2] += e2;
#pragma unroll
            for (int i = 0; i < 3; i++) {
                fma4(acc[0][i], e0, cr[rr][i]);
                fma4(acc[1][i], e1, cr[rr][i]);
                fma4(acc[2][i], e2, cr[rr][i]);
            }
        }
    }
    if (lane == 0) {
        float* zp = zpart + ((long)(b * 16 + c) * 8 + wave) * 3;
        zp[0] = zacc[0]; zp[1] = zacc[1]; zp[2] = zacc[2];
    }
    if (wave == 0) {
#pragma unroll
        for (int k = 0; k < 3; k++)
#pragma unroll
            for (int i = 0; i < 3; i++) red[k][lane + i * 64] = acc[k][i];
    }
    __syncthreads();
#pragma unroll 1
    for (int wv = 1; wv < 8; wv++) {
        if (wave == wv) {
#pragma unroll
            for (int k = 0; k < 3; k++)
#pragma unroll
                for (int i = 0; i < 3; i++) {
                    float4 r = red[k][lane + i * 64];
                    r.x += acc[k][i].x; r.y += acc[k][i].y;
                    r.z += acc[k][i].z; r.w += acc[k][i].w;
                    red[k][lane + i * 64] = r;
                }
        }
        __syncthreads();
    }
    for (int idx = t; idx < 576; idx += 512) {
        int k = idx / 192, col = idx - k * 192;
        ((float4*)pvec)[((long)(b * 16 + c) * 3 + k) * 192 + col] = red[k][col];
    }
}

// ---------------------------------------------------------------------------
// Combine chunk partials, l2-normalize -> A6; write attentions output.
// grid = (BATCH, 3). (R10-proven)
// ---------------------------------------------------------------------------
__global__ __launch_bounds__(256) void combine_norm(
        const float* __restrict__ zpart, const float* __restrict__ pvec,
        const float* __restrict__ w,
        const float* __restrict__ qm1, const float* __restrict__ qm2,
        float* __restrict__ A6, float* __restrict__ attn_out) {
    const int b = blockIdx.x, k = blockIdx.y;
    const int t = threadIdx.x;
    const int lane = t & 63, wid = t >> 6;
    __shared__ float r1[4], r2[4];
    float z = 0.f;
    for (int j = t; j < 128; j += 256)
        z += zpart[((long)b * 128 + j) * 3 + k];
    z = wave_sum(z);
    if (lane == 0) r1[wid] = z;
    __syncthreads();
    z = r1[0] + r1[1] + r1[2] + r1[3];
    float v[3] = {0.f, 0.f, 0.f};
    for (int cch = 0; cch < 16; cch++) {
        const float* p = pvec + ((long)(b * 16 + cch) * 3 + k) * DIM;
#pragma unroll
        for (int i = 0; i < 3; i++) v[i] += p[t + i * 256];
    }
    float ss = v[0] * v[0] + v[1] * v[1] + v[2] * v[2];
    float wss = wave_sum(ss);
    if (lane == 0) r2[wid] = wss;
    __syncthreads();
    ss = r2[0] + r2[1] + r2[2] + r2[3];
    float inv = 1.f / fmaxf(sqrtf(ss), 1e-12f);
#pragma unroll
    for (int i = 0; i < 3; i++) {
        int jj = t + i * 256;
        float nv = v[i] * inv;
        if (k == 0) {
            A6[(long)b * (2 * DIM) + DIM + jj] = nv;
            A6[(long)(32 + b) * (2 * DIM) + DIM + jj] = nv;
        } else if (k == 1) {
            A6[(long)b * (2 * DIM) + jj] = nv;
        } else {
            A6[(long)(32 + b) * (2 * DIM) + jj] = nv;
        }
    }
    float iz = 1.f / z;
#pragma unroll
    for (int ii = 0; ii < 8; ii++) {
        int s = t + ii * 256;
        float wv = w[(long)b * SEQ + s];
        float m1 = qm1[(long)b * SEQ + s];
        float m2 = qm2[(long)b * SEQ + s];
        bool act = (k == 0) ? (m1 != 0.f || m2 != 0.f) : (k == 1) ? (m1 != 0.f) : (m2 != 0.f);
        attn_out[((long)b * 3 + k) * SEQ + s] = act ? __expf(wv) * iz : 0.f;
    }
}

extern "C" void kernel_launch(void* const* d_in, const int* in_sizes, int n_in,
                              void* d_out, int out_size, void* d_ws, size_t ws_size,
                              hipStream_t stream) {
    const int*   step     = (const int*)  d_in[0];
    const float* ctx      = (const float*)d_in[1];
    const float* question = (const float*)d_in[2];
    const float* control  = (const float*)d_in[3];
    const float* qm1      = (const float*)d_in[4];
    const float* qm2      = (const float*)d_in[5];
    const float* W_pos    = (const float*)d_in[8];
    const float* b_pos    = (const float*)d_in[9];
    const float* ln1_g    = (const float*)d_in[10];
    const float* ln1_b    = (const float*)d_in[11];
    const float* W_cq     = (const float*)d_in[12];
    const float* b_cq     = (const float*)d_in[13];
    const float* ln2_g    = (const float*)d_in[14];
    const float* ln2_b    = (const float*)d_in[15];
    const float* W_attn   = (const float*)d_in[16];
    const float* b_attn   = (const float*)d_in[17];
    const float* W_fuse   = (const float*)d_in[18];
    const float* b_fuse   = (const float*)d_in[19];
    const float* ln3_g    = (const float*)d_in[20];
    const float* ln3_b    = (const float*)d_in[21];
    const float* ln4_g    = (const float*)d_in[22];
    const float* ln4_b    = (const float*)d_in[23];

    float* ws    = (float*)d_ws;
    float* w     = ws;             // 32*2048  = 65536
    float* zpart = ws + 65536;     // 32*128*3 = 12288
    float* A6    = ws + 77824;     // 64*1536  = 98304
    float* part1 = ws + 176128;    // 4*32*768 = 98304
    float* part2 = ws + 274432;    // 36*32*768 = 884736
    float* big   = ws + 1159168;   // pvec / gemm3 partials (1179648)

    float* nc_out   = (float*)d_out;
    float* attn_out = (float*)d_out + BATCH * 2 * DIM;

    // K1: gemm1 || gemm2-control (independent)
    k1_kernel<<<336, 256, 0, stream>>>(
        question, W_pos, step, control, W_cq, part1, part2);

    // K2: LN1 fold + gemm2-pa -> part2[24..35]
    gemm2pa_kernel<<<144, 256, 0, stream>>>(
        part1, b_pos, step, ln1_g, ln1_b, W_cq, part2);

    // fused LN2 + single-read attention
    attn_main<<<dim3(SEQ / 128, BATCH), 512, 0, stream>>>(
        ctx, part2, b_cq, ln2_g, ln2_b, W_attn, b_attn, qm1, qm2, w, zpart, big);

    // combine + l2norm -> A6; attentions output
    combine_norm<<<dim3(BATCH, 3), 256, 0, stream>>>(
        zpart, big, w, qm1, qm2, A6, attn_out);

    // gemm3 + dual-LN -> next_control
    gemm_partial<<<dim3(DIM / 64, 2, (2 * DIM) / 64), 256, 0, stream>>>(
        A6, 2 * DIM, W_fuse, big, 64);
    reduce_ln_final<<<2 * BATCH, 256, 0, stream>>>(big, (2 * DIM) / 64, b_fuse,
                                                   ln3_g, ln3_b, ln4_g, ln4_b, nc_out);
}

// Round 13
// 94.518 us; speedup vs baseline: 1.1428x; 1.1428x over previous
//
#include <hip/hip_runtime.h>
#include <hip/hip_bf16.h>
#include <math.h>

#define DIM   768
#define BATCH 32
#define SEQ   2048
#define SCALE 0.036084391824351615f  // 1/sqrt(768)

__device__ __forceinline__ float wave_sum(float v) {
#pragma unroll
    for (int o = 32; o > 0; o >>= 1) v += __shfl_xor(v, o, 64);
    return v;
}

__device__ __forceinline__ void fma4(float4& a, float s, const float4& c) {
    a.x += s * c.x; a.y += s * c.y; a.z += s * c.z; a.w += s * c.w;
}

// ---------------------------------------------------------------------------
// Split-K partial GEMM with dual-source A (concat along K at ksplit):
// part[kc][Mtot][768] = A[M x 64-chunk] @ W[chunk x 768]
// grid = (768/64, Mtot/32, K/64), block = 256.  (R3-proven)
// ---------------------------------------------------------------------------
__global__ __launch_bounds__(256) void gemm_partial(
        const float* __restrict__ A0, int lda0,
        const float* __restrict__ A1, int lda1, int ksplit,
        const float* __restrict__ W,
        float* __restrict__ part, int Mtot,
        const int* __restrict__ step_ptr, int wstride) {
    const float* Wp = W + (step_ptr ? (long)step_ptr[0] * wstride : 0);
    const int jt = blockIdx.x * 64;
    const int r0 = blockIdx.y * 32;
    const int kc = blockIdx.z;
    __shared__ float As[32][33];
    __shared__ float Ws[32][64];
    const int t = threadIdx.x;
    const int j = t & 63;
    const int bg = t >> 6;
    float acc[8];
#pragma unroll
    for (int i = 0; i < 8; i++) acc[i] = 0.f;

    for (int k0 = kc * 64; k0 < kc * 64 + 64; k0 += 32) {
        {   // A tile 32x32
            int r  = t >> 3;
            int kk = (t & 7) * 4;
            int ka = k0 + kk;
            float4 av;
            if (ka < ksplit)
                av = *(const float4*)(A0 + (long)(r0 + r) * lda0 + ka);
            else
                av = *(const float4*)(A1 + (long)(r0 + r) * lda1 + (ka - ksplit));
            As[r][kk] = av.x; As[r][kk + 1] = av.y; As[r][kk + 2] = av.z; As[r][kk + 3] = av.w;
        }
#pragma unroll
        for (int i = 0; i < 2; i++) {  // W tile 32x64, float4 loads
            int idx = t + i * 256;
            int row = idx >> 4, col4 = idx & 15;
            float4 wv = *(const float4*)(Wp + (long)(k0 + row) * DIM + jt + col4 * 4);
            *(float4*)&Ws[row][col4 * 4] = wv;
        }
        __syncthreads();
#pragma unroll 8
        for (int kk = 0; kk < 32; kk++) {
            float wv = Ws[kk][j];
#pragma unroll
            for (int i = 0; i < 8; i++) acc[i] += As[bg * 8 + i][kk] * wv;
        }
        __syncthreads();
    }
#pragma unroll
    for (int i = 0; i < 8; i++)
        part[((long)(kc * Mtot + r0 + bg * 8 + i)) * DIM + jt + j] = acc[i];
}

// ---------------------------------------------------------------------------
// Reduce split-K partials + bias, LayerNorm+ReLU (+optional *wattn fold).
// grid = Mtot, block = 256.  (R3-proven; used for LN1 only)
// ---------------------------------------------------------------------------
__global__ __launch_bounds__(256) void reduce_ln(
        const float* __restrict__ part, int KC, int Mtot,
        const float* __restrict__ bias,
        const int* __restrict__ step_ptr, int bstride,
        const float* __restrict__ g, const float* __restrict__ b,
        const float* __restrict__ wattn,
        float* __restrict__ out) {
    const int row = blockIdx.x;
    const int t = threadIdx.x;
    const float* bp = bias + (step_ptr ? (long)step_ptr[0] * bstride : 0);
    __shared__ float r1[4], r2[4];
    float x[3];
    float s = 0.f, ss = 0.f;
#pragma unroll
    for (int i = 0; i < 3; i++) {
        int jj = t + i * 256;
        float v = bp[jj];
#pragma unroll 4
        for (int kc = 0; kc < KC; kc++)
            v += part[((long)(kc * Mtot + row)) * DIM + jj];
        x[i] = v; s += v; ss += v * v;
    }
    float wsv = wave_sum(s), wss = wave_sum(ss);
    int lane = t & 63, wid = t >> 6;
    if (lane == 0) { r1[wid] = wsv; r2[wid] = wss; }
    __syncthreads();
    s  = r1[0] + r1[1] + r1[2] + r1[3];
    ss = r2[0] + r2[1] + r2[2] + r2[3];
    float mu = s * (1.f / DIM);
    float var = ss * (1.f / DIM) - mu * mu;
    float rs = rsqrtf(var + 1e-5f);
#pragma unroll
    for (int i = 0; i < 3; i++) {
        int jj = t + i * 256;
        float y = (x[i] - mu) * rs * g[jj] + b[jj];
        y = y > 0.f ? y : 0.f;
        if (wattn) y *= wattn[jj];
        out[(long)row * DIM + jj] = y;
    }
}

// Final: reduce + bias, dual LN, ReLU -> next_control. grid = 64, block 256.
__global__ __launch_bounds__(256) void reduce_ln_final(
        const float* __restrict__ part, int KC,
        const float* __restrict__ bias,
        const float* __restrict__ g3, const float* __restrict__ b3,
        const float* __restrict__ g4, const float* __restrict__ b4,
        float* __restrict__ nc) {
    const int row = blockIdx.x;  // 0..63
    const int t = threadIdx.x;
    __shared__ float r1[4], r2[4];
    float x[3];
    float s = 0.f, ss = 0.f;
#pragma unroll
    for (int i = 0; i < 3; i++) {
        int jj = t + i * 256;
        float v = bias[jj];
#pragma unroll 4
        for (int kc = 0; kc < KC; kc++)
            v += part[((long)(kc * 64 + row)) * DIM + jj];
        x[i] = v; s += v; ss += v * v;
    }
    float wsv = wave_sum(s), wss = wave_sum(ss);
    int lane = t & 63, wid = t >> 6;
    if (lane == 0) { r1[wid] = wsv; r2[wid] = wss; }
    __syncthreads();
    s  = r1[0] + r1[1] + r1[2] + r1[3];
    ss = r2[0] + r2[1] + r2[2] + r2[3];
    float mu = s * (1.f / DIM);
    float var = ss * (1.f / DIM) - mu * mu;
    float rs = rsqrtf(var + 1e-5f);
    const float* g  = (row < 32) ? g3 : g4;
    const float* bb = (row < 32) ? b3 : b4;
    int bidx = row & 31;
    int off  = (row < 32) ? 0 : DIM;
#pragma unroll
    for (int i = 0; i < 3; i++) {
        int jj = t + i * 256;
        float y = (x[i] - mu) * rs * g[jj] + bb[jj];
        nc[(long)bidx * (2 * DIM) + off + jj] = y > 0.f ? y : 0.f;
    }
}

// ---------------------------------------------------------------------------
// Fused attention with LN2 folded in (R11-proven, best measured config):
// each block reduces part2 -> u[b] in LDS (36 chunks + b_cq -> LN -> ReLU
// -> *W_attn), then the single-ctx-read attention.
// grid = (SEQ/128, BATCH), 512 threads (8 waves), CHUNK=128.
// ---------------------------------------------------------------------------
__global__ __launch_bounds__(512, 4) void attn_main(
        const float* __restrict__ ctx, const float* __restrict__ part2,
        const float* __restrict__ b_cq,
        const float* __restrict__ ln2_g, const float* __restrict__ ln2_b,
        const float* __restrict__ W_attn, const float* __restrict__ b_attn,
        const float* __restrict__ qm1, const float* __restrict__ qm2,
        float* __restrict__ w, float* __restrict__ zpart,
        float* __restrict__ pvec) {
    const int c = blockIdx.x;   // 0..15
    const int b = blockIdx.y;
    const int t = threadIdx.x;
    const int wave = t >> 6, lane = t & 63;
    __shared__ float4 red[3][192];   // 9216 B
    __shared__ float ush[DIM];       // 3072 B
    __shared__ float sc1[8], sc2[8];

    // ---- LN2 preamble: u[b] from part2 ----
    {
        float ua = b_cq[t];
        float ub = (t < 256) ? b_cq[t + 512] : 0.f;
#pragma unroll 4
        for (int kc = 0; kc < 36; kc++) {
            const float* p2 = part2 + ((long)(kc * 32 + b)) * DIM;
            ua += p2[t];
            if (t < 256) ub += p2[t + 512];
        }
        float v1 = wave_sum(ua + ub);
        float v2 = wave_sum(ua * ua + ub * ub);
        if (lane == 0) { sc1[wave] = v1; sc2[wave] = v2; }
        __syncthreads();
        float s = 0.f, ss = 0.f;
#pragma unroll
        for (int i = 0; i < 8; i++) { s += sc1[i]; ss += sc2[i]; }
        float mu = s * (1.f / DIM);
        float var = ss * (1.f / DIM) - mu * mu;
        float rs = rsqrtf(var + 1e-5f);
        float y = (ua - mu) * rs * ln2_g[t] + ln2_b[t];
        ush[t] = (y > 0.f ? y : 0.f) * W_attn[t];
        if (t < 256) {
            float y2 = (ub - mu) * rs * ln2_g[t + 512] + ln2_b[t + 512];
            ush[t + 512] = (y2 > 0.f ? y2 : 0.f) * W_attn[t + 512];
        }
        __syncthreads();
    }

    const float batt = b_attn[0];
    const long row0 = (long)b * SEQ + c * 128;

    float4 uu[3];
#pragma unroll
    for (int i = 0; i < 3; i++)
        uu[i] = ((const float4*)ush)[lane + i * 64];

    float4 acc[3][3];
#pragma unroll
    for (int k = 0; k < 3; k++)
#pragma unroll
        for (int i = 0; i < 3; i++) acc[k][i] = make_float4(0.f, 0.f, 0.f, 0.f);
    float zacc[3] = {0.f, 0.f, 0.f};

#pragma unroll 1
    for (int g = 0; g < 4; g++) {
        const int rw = g * 32 + wave * 4;   // 8 waves x 4 rows x 4 groups = 128
        float4 cr[4][3];
        float d[4];
#pragma unroll
        for (int rr = 0; rr < 4; rr++) {
            const float4* crow = (const float4*)(ctx + (row0 + rw + rr) * DIM);
            float dd = 0.f;
#pragma unroll
            for (int i = 0; i < 3; i++) {
                float4 cv = crow[lane + i * 64];
                cr[rr][i] = cv;
                dd += cv.x * uu[i].x + cv.y * uu[i].y + cv.z * uu[i].z + cv.w * uu[i].w;
            }
            d[rr] = wave_sum(dd);
        }
        float lw0 = (d[0] + batt) * SCALE;
        float lw1 = (d[1] + batt) * SCALE;
        float lw2 = (d[2] + batt) * SCALE;
        float lw3 = (d[3] + batt) * SCALE;
        if (lane < 4) {
            float v = lane == 0 ? lw0 : lane == 1 ? lw1 : lane == 2 ? lw2 : lw3;
            w[row0 + rw + lane] = v;
        }
        // masks for the 4 rows: lanes 0-3 qm1, lanes 4-7 qm2
        float mv = 0.f;
        if (lane < 4) mv = qm1[row0 + rw + lane];
        else if (lane < 8) mv = qm2[row0 + rw + lane - 4];
#pragma unroll
        for (int rr = 0; rr < 4; rr++) {
            float a1 = __shfl(mv, rr, 64);
            float a2 = __shfl(mv, rr + 4, 64);
            float lwr = rr == 0 ? lw0 : rr == 1 ? lw1 : rr == 2 ? lw2 : lw3;
            float ev = __expf(lwr);
            float e0 = (a1 != 0.f || a2 != 0.f) ? ev : 0.f;
            float e1 = (a1 != 0.f) ? ev : 0.f;
            float e2 = (a2 != 0.f) ? ev : 0.f;
            zacc[0] += e0; zacc[1] += e1; zacc[2] += e2;
#pragma unroll
            for (int i = 0; i < 3; i++) {
                fma4(acc[0][i], e0, cr[rr][i]);
                fma4(acc[1][i], e1, cr[rr][i]);
                fma4(acc[2][i], e2, cr[rr][i]);
            }
        }
    }
    if (lane == 0) {
        float* zp = zpart + ((long)(b * 16 + c) * 8 + wave) * 3;
        zp[0] = zacc[0]; zp[1] = zacc[1]; zp[2] = zacc[2];
    }
    // cross-wave reduce: wave 0 seeds, waves 1-7 add sequentially
    if (wave == 0) {
#pragma unroll
        for (int k = 0; k < 3; k++)
#pragma unroll
            for (int i = 0; i < 3; i++) red[k][lane + i * 64] = acc[k][i];
    }
    __syncthreads();
#pragma unroll 1
    for (int wv = 1; wv < 8; wv++) {
        if (wave == wv) {
#pragma unroll
            for (int k = 0; k < 3; k++)
#pragma unroll
                for (int i = 0; i < 3; i++) {
                    float4 r = red[k][lane + i * 64];
                    r.x += acc[k][i].x; r.y += acc[k][i].y;
                    r.z += acc[k][i].z; r.w += acc[k][i].w;
                    red[k][lane + i * 64] = r;
                }
        }
        __syncthreads();
    }
    for (int idx = t; idx < 576; idx += 512) {
        int k = idx / 192, col = idx - k * 192;
        ((float4*)pvec)[((long)(b * 16 + c) * 3 + k) * 192 + col] = red[k][col];
    }
}

// ---------------------------------------------------------------------------
// Combine chunk partials, l2-normalize -> A6; write attentions output.
// grid = (BATCH, 3): k=0 ncf, k=1 mc1, k=2 mc2. block = 256.
// ---------------------------------------------------------------------------
__global__ __launch_bounds__(256) void combine_norm(
        const float* __restrict__ zpart, const float* __restrict__ pvec,
        const float* __restrict__ w,
        const float* __restrict__ qm1, const float* __restrict__ qm2,
        float* __restrict__ A6, float* __restrict__ attn_out) {
    const int b = blockIdx.x, k = blockIdx.y;
    const int t = threadIdx.x;
    const int lane = t & 63, wid = t >> 6;
    __shared__ float r1[4], r2[4];
    // softmax denominator: 128 contiguous entries per b
    float z = 0.f;
    for (int j = t; j < 128; j += 256)
        z += zpart[((long)b * 128 + j) * 3 + k];
    z = wave_sum(z);
    if (lane == 0) r1[wid] = z;
    __syncthreads();
    z = r1[0] + r1[1] + r1[2] + r1[3];
    // vector combine over 16 chunks
    float v[3] = {0.f, 0.f, 0.f};
    for (int cch = 0; cch < 16; cch++) {
        const float* p = pvec + ((long)(b * 16 + cch) * 3 + k) * DIM;
#pragma unroll
        for (int i = 0; i < 3; i++) v[i] += p[t + i * 256];
    }
    float ss = v[0] * v[0] + v[1] * v[1] + v[2] * v[2];
    float wss = wave_sum(ss);
    if (lane == 0) r2[wid] = wss;
    __syncthreads();
    ss = r2[0] + r2[1] + r2[2] + r2[3];
    float inv = 1.f / fmaxf(sqrtf(ss), 1e-12f);
#pragma unroll
    for (int i = 0; i < 3; i++) {
        int jj = t + i * 256;
        float nv = v[i] * inv;
        if (k == 0) {
            A6[(long)b * (2 * DIM) + DIM + jj] = nv;
            A6[(long)(32 + b) * (2 * DIM) + DIM + jj] = nv;
        } else if (k == 1) {
            A6[(long)b * (2 * DIM) + jj] = nv;
        } else {
            A6[(long)(32 + b) * (2 * DIM) + jj] = nv;
        }
    }
    // attentions output for this (b, k)
    float iz = 1.f / z;
#pragma unroll
    for (int ii = 0; ii < 8; ii++) {
        int s = t + ii * 256;
        float wv = w[(long)b * SEQ + s];
        float m1 = qm1[(long)b * SEQ + s];
        float m2 = qm2[(long)b * SEQ + s];
        bool act = (k == 0) ? (m1 != 0.f || m2 != 0.f) : (k == 1) ? (m1 != 0.f) : (m2 != 0.f);
        attn_out[((long)b * 3 + k) * SEQ + s] = act ? __expf(wv) * iz : 0.f;
    }
}

extern "C" void kernel_launch(void* const* d_in, const int* in_sizes, int n_in,
                              void* d_out, int out_size, void* d_ws, size_t ws_size,
                              hipStream_t stream) {
    const int*   step     = (const int*)  d_in[0];
    const float* ctx      = (const float*)d_in[1];
    const float* question = (const float*)d_in[2];
    const float* control  = (const float*)d_in[3];
    const float* qm1      = (const float*)d_in[4];
    const float* qm2      = (const float*)d_in[5];
    const float* W_pos    = (const float*)d_in[8];
    const float* b_pos    = (const float*)d_in[9];
    const float* ln1_g    = (const float*)d_in[10];
    const float* ln1_b    = (const float*)d_in[11];
    const float* W_cq     = (const float*)d_in[12];
    const float* b_cq     = (const float*)d_in[13];
    const float* ln2_g    = (const float*)d_in[14];
    const float* ln2_b    = (const float*)d_in[15];
    const float* W_attn   = (const float*)d_in[16];
    const float* b_attn   = (const float*)d_in[17];
    const float* W_fuse   = (const float*)d_in[18];
    const float* b_fuse   = (const float*)d_in[19];
    const float* ln3_g    = (const float*)d_in[20];
    const float* ln3_b    = (const float*)d_in[21];
    const float* ln4_g    = (const float*)d_in[22];
    const float* ln4_b    = (const float*)d_in[23];

    float* ws    = (float*)d_ws;
    float* pa    = ws;             // 32*768   = 24576
    float* w     = ws + 49152;     // 32*2048  = 65536
    float* zpart = ws + 114688;    // 32*128*3 = 12288
    float* A6    = ws + 126976;    // 64*1536  = 98304
    float* part2 = ws + 225280;    // 36*32*768 = 884736 (persists through attn)
    float* big   = ws + 1110016;   // gemm1/gemm3 partials, pvec (<=1179648)

    float* nc_out   = (float*)d_out;
    float* attn_out = (float*)d_out + BATCH * 2 * DIM;

    // pa = ln_relu(question @ W_pos[step] + b_pos[step])
    gemm_partial<<<dim3(DIM / 64, 1, DIM / 64), 256, 0, stream>>>(
        question, DIM, question, DIM, 1 << 30, W_pos, big, 32, step, DIM * DIM);
    reduce_ln<<<BATCH, 256, 0, stream>>>(big, DIM / 64, 32, b_pos, step, DIM,
                                         ln1_g, ln1_b, nullptr, pa);

    // part2 = [control | pa] @ W_cq (split-K partials; LN2 folded into attn)
    gemm_partial<<<dim3(DIM / 64, 1, (3 * DIM) / 64), 256, 0, stream>>>(
        control, 2 * DIM, pa, DIM, 2 * DIM, W_cq, part2, 32, nullptr, 0);

    // fused LN2 + single-read attention (512 threads, CHUNK=128)
    attn_main<<<dim3(SEQ / 128, BATCH), 512, 0, stream>>>(
        ctx, part2, b_cq, ln2_g, ln2_b, W_attn, b_attn, qm1, qm2, w, zpart, big);

    // combine + l2norm -> A6; attentions output
    combine_norm<<<dim3(BATCH, 3), 256, 0, stream>>>(
        zpart, big, w, qm1, qm2, A6, attn_out);

    // fused GEMM + dual-LN -> next_control
    gemm_partial<<<dim3(DIM / 64, 2, (2 * DIM) / 64), 256, 0, stream>>>(
        A6, 2 * DIM, A6, 2 * DIM, 1 << 30, W_fuse, big, 64, nullptr, 0);
    reduce_ln_final<<<2 * BATCH, 256, 0, stream>>>(big, (2 * DIM) / 64, b_fuse,
                                                   ln3_g, ln3_b, ln4_g, ln4_b, nc_out);
}